// Round 1
// baseline (771.756 us; speedup 1.0000x reference)
//
#include <hip/hip_runtime.h>
#include <math.h>

// InvariantPointAttention — MI355X fp32 implementation, round 1 (correctness-first).
// B=1 assumed throughout.
#define N    384
#define DSd  384
#define DP   128
#define DH   16
#define H    12
#define PQK  4
#define PV   8
#define PKV  12
#define HC   (H*DH)          // 192
#define PROJW 1152           // 192 + 384 + 144 + 432
#define NN   (N*N)           // 147456
#define COUTD 2112           // H*(DP + DH + PV*4)

// ---------------------------------------------------------------------------
// Generic tiled fp32 GEMM: C[r, coff+c] = sum_k A[r,k]*B[k,c] + bias[c]
// A: M x K row-major (M must be a multiple of 64; K a multiple of 32).
// B: K x Nc row-major. C row stride = ldc. Bounds-checked in Nc only.
__global__ __launch_bounds__(256) void gemm_f32(
    const float* __restrict__ A, const float* __restrict__ B,
    const float* __restrict__ bias, float* __restrict__ C,
    int M, int Nc, int K, int ldc, int coff)
{
    __shared__ float As[64][33];   // +1 pad: conflict-free column reads
    __shared__ float Bs[32][65];
    const int tid = threadIdx.x;
    const int tx = tid & 15, ty = tid >> 4;
    const int row0 = blockIdx.x * 64, col0 = blockIdx.y * 64;
    float acc[4][4] = {};

    for (int kk = 0; kk < K; kk += 32) {
        #pragma unroll
        for (int i = tid; i < 64*32; i += 256) {
            int r = i >> 5, c = i & 31;
            As[r][c] = A[(row0 + r) * K + kk + c];
        }
        #pragma unroll
        for (int i = tid; i < 32*64; i += 256) {
            int r = i >> 6, c = i & 63;
            int gc = col0 + c;
            Bs[r][c] = (gc < Nc) ? B[(kk + r) * Nc + gc] : 0.f;
        }
        __syncthreads();
        #pragma unroll
        for (int p = 0; p < 32; ++p) {
            float av[4], bv[4];
            #pragma unroll
            for (int i = 0; i < 4; ++i) av[i] = As[ty*4 + i][p];
            #pragma unroll
            for (int j = 0; j < 4; ++j) bv[j] = Bs[p][tx*4 + j];
            #pragma unroll
            for (int i = 0; i < 4; ++i)
                #pragma unroll
                for (int j = 0; j < 4; ++j)
                    acc[i][j] = fmaf(av[i], bv[j], acc[i][j]);
        }
        __syncthreads();
    }
    #pragma unroll
    for (int i = 0; i < 4; ++i) {
        int gr = row0 + ty*4 + i;
        #pragma unroll
        for (int j = 0; j < 4; ++j) {
            int gc = col0 + tx*4 + j;
            if (gc < Nc)
                C[gr * ldc + coff + gc] = acc[i][j] + (bias ? bias[gc] : 0.f);
        }
    }
}

// ---------------------------------------------------------------------------
// Repack projections + apply frame rotation to points.
// proj row layout: [0,192) q | [192,576) kv (h-major, k then v 16 each)
//                 | [576,720) q_pts lin (3 x 48) | [720,1152) kv_pts lin (3 x 144)
__global__ __launch_bounds__(192) void repack_kernel(
    const float* __restrict__ proj, const float* __restrict__ rot,
    const float* __restrict__ trans,
    float* __restrict__ q_t, float* __restrict__ k_t, float* __restrict__ v_t,
    float* __restrict__ qpts_t, float* __restrict__ kpts_t, float* __restrict__ vpts_t)
{
    const int n = blockIdx.x;
    const int tid = threadIdx.x;
    const float* pr = proj + n * PROJW;

    {   // q/k/v transpose to (H, N, DH)
        int h = tid >> 4, d = tid & 15;
        q_t[(h*N + n)*DH + d] = pr[h*DH + d];
        k_t[(h*N + n)*DH + d] = pr[HC + h*2*DH + d];
        v_t[(h*N + n)*DH + d] = pr[HC + h*2*DH + DH + d];
    }
    const float r00 = rot[n*9+0], r01 = rot[n*9+1], r02 = rot[n*9+2];
    const float r10 = rot[n*9+3], r11 = rot[n*9+4], r12 = rot[n*9+5];
    const float r20 = rot[n*9+6], r21 = rot[n*9+7], r22 = rot[n*9+8];
    const float t0 = trans[n*3+0], t1 = trans[n*3+1], t2 = trans[n*3+2];

    if (tid < H*PQK) {  // 48 query points
        int p = tid;
        float l0 = pr[576 + 0*48 + p];
        float l1 = pr[576 + 1*48 + p];
        float l2 = pr[576 + 2*48 + p];
        int h = p / PQK, pt = p % PQK;
        float* dst = qpts_t + (h*N + n)*12 + pt*3;
        dst[0] = r00*l0 + r01*l1 + r02*l2 + t0;
        dst[1] = r10*l0 + r11*l1 + r12*l2 + t1;
        dst[2] = r20*l0 + r21*l1 + r22*l2 + t2;
    }
    if (tid < H*PKV) {  // 144 kv points
        int p = tid;
        float l0 = pr[720 + 0*144 + p];
        float l1 = pr[720 + 1*144 + p];
        float l2 = pr[720 + 2*144 + p];
        int h = p / PKV, pt = p % PKV;
        float x0 = r00*l0 + r01*l1 + r02*l2 + t0;
        float x1 = r10*l0 + r11*l1 + r12*l2 + t1;
        float x2 = r20*l0 + r21*l1 + r22*l2 + t2;
        if (pt < PQK) {
            float* dst = kpts_t + (h*N + n)*12 + pt*3;
            dst[0] = x0; dst[1] = x1; dst[2] = x2;
        } else {
            float* dst = vpts_t + (h*N + n)*24 + (pt - PQK)*3;
            dst[0] = x0; dst[1] = x1; dst[2] = x2;
        }
    }
}

// ---------------------------------------------------------------------------
// bias_t[h][pair] = (z[pair,:] . Wb[:,h] + bb[h]) * sqrt(1/3)
// Stored pre-transposed + pre-scaled to (H, N, N) so attn reads are coalesced.
__global__ __launch_bounds__(256) void bias_kernel(
    const float* __restrict__ z, const float* __restrict__ Wb,
    const float* __restrict__ bb, float* __restrict__ biasattn)
{
    __shared__ float zt[64][129];   // +1 pad -> (p+c)%32 banks, 2-way max (free)
    __shared__ float wb[DP*H];
    const int tid = threadIdx.x;
    const int base = blockIdx.x * 64;
    for (int i = tid; i < DP*H; i += 256) wb[i] = Wb[i];
    for (int i = tid; i < 64*DP; i += 256)
        zt[i >> 7][i & 127] = z[base*DP + i];        // fully coalesced
    __syncthreads();

    const int p = tid & 63, g = tid >> 6;            // g: 3 heads each
    float a0 = 0.f, a1 = 0.f, a2 = 0.f;
    #pragma unroll 8
    for (int c = 0; c < DP; ++c) {
        float zv = zt[p][c];
        a0 = fmaf(zv, wb[c*H + g*3 + 0], a0);
        a1 = fmaf(zv, wb[c*H + g*3 + 1], a1);
        a2 = fmaf(zv, wb[c*H + g*3 + 2], a2);
    }
    const float sc = 0.5773502691896258f;            // sqrt(1/3)
    const int pair = base + p;
    biasattn[(g*3+0)*NN + pair] = (a0 + bb[g*3+0]) * sc;
    biasattn[(g*3+1)*NN + pair] = (a1 + bb[g*3+1]) * sc;
    biasattn[(g*3+2)*NN + pair] = (a2 + bb[g*3+2]) * sc;
}

// ---------------------------------------------------------------------------
// Per (h, q): logits over k (qk dot + bias + mask + point term), softmax,
// write attention in place over the bias buffer (block owns its row).
__global__ __launch_bounds__(128) void attn_kernel(
    const float* __restrict__ q_t, const float* __restrict__ k_t,
    const float* __restrict__ qpts_t, const float* __restrict__ kpts_t,
    const float* __restrict__ mask, const float* __restrict__ head_weights,
    float* __restrict__ biasattn)
{
    const int h  = blockIdx.x % H;
    const int qi = blockIdx.x / H;
    const int tid = threadIdx.x;
    __shared__ float qv[DH];
    __shared__ float qp[12];
    __shared__ float logits[N];
    __shared__ float red[128];

    if (tid < DH) qv[tid] = q_t[(h*N + qi)*DH + tid];
    if (tid < 12) qp[tid] = qpts_t[(h*N + qi)*12 + tid];
    __syncthreads();
    const float hw = log1pf(expf(head_weights[h])) * 0.13608276348795434f; // sqrt(1/54)

    float lmax = -1e30f;
    for (int k = tid; k < N; k += 128) {
        const float* kr = k_t + (h*N + k)*DH;
        float dot = 0.f;
        #pragma unroll
        for (int d = 0; d < DH; ++d) dot = fmaf(qv[d], kr[d], dot);
        const float* kp = kpts_t + (h*N + k)*12;
        float d2 = 0.f;
        #pragma unroll
        for (int t = 0; t < 12; ++t) { float df = qp[t] - kp[t]; d2 = fmaf(df, df, d2); }
        float l = dot * 0.14433756729740643f          // sqrt(1/(3*16))
                + biasattn[h*NN + qi*N + k]           // already *sqrt(1/3)
                + mask[qi*N + k]
                - 0.5f * hw * d2;
        logits[k] = l;
        lmax = fmaxf(lmax, l);
    }
    red[tid] = lmax; __syncthreads();
    for (int s = 64; s > 0; s >>= 1) {
        if (tid < s) red[tid] = fmaxf(red[tid], red[tid + s]);
        __syncthreads();
    }
    const float m = red[0];
    __syncthreads();
    float lsum = 0.f;
    for (int k = tid; k < N; k += 128) {
        float e = expf(logits[k] - m);
        logits[k] = e;
        lsum += e;
    }
    red[tid] = lsum; __syncthreads();
    for (int s = 64; s > 0; s >>= 1) {
        if (tid < s) red[tid] += red[tid + s];
        __syncthreads();
    }
    const float inv = 1.f / red[0];
    for (int k = tid; k < N; k += 128)
        biasattn[h*NN + qi*N + k] = logits[k] * inv;
}

// ---------------------------------------------------------------------------
// Per q: o (12x16), o_pts (12x8x3, inverse frame + norms), o_pair (12x128),
// assembled into the 2112-wide cat row.
__global__ __launch_bounds__(256) void out_accum_kernel(
    const float* __restrict__ attn, const float* __restrict__ v_t,
    const float* __restrict__ vpts_t, const float* __restrict__ z,
    const float* __restrict__ rot, const float* __restrict__ trans,
    float* __restrict__ cat)
{
    const int qi = blockIdx.x;
    const int tid = threadIdx.x;
    __shared__ float at[H][N + 1];      // +1 pad: (h+k)%32 banks
    __shared__ float catv[COUTD];
    __shared__ float praw[H*PV*3];

    for (int i = tid; i < H*N; i += 256)
        at[i / N][i % N] = attn[(i / N)*NN + qi*N + (i % N)];
    __syncthreads();

    {   // o_pair: lanes 0..127 own channel c; two thread-halves split 12 heads
        const int c = tid & 127, g = tid >> 7;
        float acc[6] = {};
        const float* zr = z + qi*N*DP + c;
        for (int k = 0; k < N; ++k) {
            float zv = zr[k*DP];                    // coalesced over c
            #pragma unroll
            for (int j = 0; j < 6; ++j)
                acc[j] = fmaf(at[g*6 + j][k], zv, acc[j]);
        }
        #pragma unroll
        for (int j = 0; j < 6; ++j)
            catv[576 + (g*6 + j)*DP + c] = acc[j];
    }
    if (tid < H*DH) {   // o
        const int h = tid >> 4, d = tid & 15;
        float acc = 0.f;
        for (int k = 0; k < N; ++k)
            acc = fmaf(at[h][k], v_t[(h*N + k)*DH + d], acc);
        catv[h*DH + d] = acc;
    }
    for (int j = tid; j < H*PV*3; j += 256) {   // o_pts accumulate (lab frame)
        const int h = j / 24, r = j % 24;
        float acc = 0.f;
        for (int k = 0; k < N; ++k)
            acc = fmaf(at[h][k], vpts_t[(h*N + k)*24 + r], acc);
        praw[j] = acc;
    }
    __syncthreads();
    if (tid < H*PV) {   // inverse rotation (rot^T), translate, norm
        const float* rr = rot + qi*9;
        const float t0 = trans[qi*3+0], t1 = trans[qi*3+1], t2 = trans[qi*3+2];
        float y0 = praw[tid*3+0] - t0;
        float y1 = praw[tid*3+1] - t1;
        float y2 = praw[tid*3+2] - t2;
        float f0 = rr[0]*y0 + rr[3]*y1 + rr[6]*y2;
        float f1 = rr[1]*y0 + rr[4]*y1 + rr[7]*y2;
        float f2 = rr[2]*y0 + rr[5]*y1 + rr[8]*y2;
        catv[HC + 0*96 + tid] = f0;
        catv[HC + 1*96 + tid] = f1;
        catv[HC + 2*96 + tid] = f2;
        catv[HC + 3*96 + tid] = sqrtf(f0*f0 + f1*f1 + f2*f2 + 1e-8f);
    }
    __syncthreads();
    float* dst = cat + qi * COUTD;
    for (int i = tid; i < COUTD; i += 256) dst[i] = catv[i];
}

// ---------------------------------------------------------------------------
extern "C" void kernel_launch(void* const* d_in, const int* in_sizes, int n_in,
                              void* d_out, int out_size, void* d_ws, size_t ws_size,
                              hipStream_t stream)
{
    const float* s       = (const float*)d_in[0];
    const float* z       = (const float*)d_in[1];
    const float* rot     = (const float*)d_in[2];
    const float* trans   = (const float*)d_in[3];
    const float* mask    = (const float*)d_in[4];
    const float* Wq      = (const float*)d_in[5];
    const float* bq      = (const float*)d_in[6];
    const float* Wkv     = (const float*)d_in[7];
    const float* bkv     = (const float*)d_in[8];
    const float* Wq_pts  = (const float*)d_in[9];
    const float* bq_pts  = (const float*)d_in[10];
    const float* Wkv_pts = (const float*)d_in[11];
    const float* bkv_pts = (const float*)d_in[12];
    const float* Wb      = (const float*)d_in[13];
    const float* bb      = (const float*)d_in[14];
    const float* hwts    = (const float*)d_in[15];
    const float* Wout    = (const float*)d_in[16];
    const float* bout    = (const float*)d_in[17];
    float* out = (float*)d_out;
    float* ws  = (float*)d_ws;

    // workspace layout (floats); total 3,465,216 f32 ~= 13.9 MB
    float* proj   = ws;                  // N x 1152
    float* q_t    = proj   + 442368;     // H x N x 16
    float* k_t    = q_t    + 73728;
    float* v_t    = k_t    + 73728;
    float* qpts_t = v_t    + 73728;      // H x N x 12
    float* kpts_t = qpts_t + 55296;      // H x N x 12
    float* vpts_t = kpts_t + 55296;      // H x N x 24
    float* ba     = vpts_t + 110592;     // H x N x N (bias, then attn in place)
    float* cat    = ba     + 1769472;    // N x 2112

    // s-projections into packed proj rows
    gemm_f32<<<dim3(6,3), 256, 0, stream>>>(s, Wq,      bq,      proj, N, 192, DSd, PROJW, 0);
    gemm_f32<<<dim3(6,6), 256, 0, stream>>>(s, Wkv,     bkv,     proj, N, 384, DSd, PROJW, 192);
    gemm_f32<<<dim3(6,3), 256, 0, stream>>>(s, Wq_pts,  bq_pts,  proj, N, 144, DSd, PROJW, 576);
    gemm_f32<<<dim3(6,7), 256, 0, stream>>>(s, Wkv_pts, bkv_pts, proj, N, 432, DSd, PROJW, 720);

    repack_kernel<<<N, 192, 0, stream>>>(proj, rot, trans, q_t, k_t, v_t, qpts_t, kpts_t, vpts_t);
    bias_kernel<<<NN/64, 256, 0, stream>>>(z, Wb, bb, ba);
    attn_kernel<<<N*H, 128, 0, stream>>>(q_t, k_t, qpts_t, kpts_t, mask, hwts, ba);
    out_accum_kernel<<<N, 256, 0, stream>>>(ba, v_t, vpts_t, z, rot, trans, cat);

    // final projection: cat (384 x 2112) @ Wout (2112 x 384) + bout
    gemm_f32<<<dim3(6,6), 256, 0, stream>>>(cat, Wout, bout, out, N, 384, COUTD, 384, 0);
}

// Round 2
// 403.492 us; speedup vs baseline: 1.9127x; 1.9127x over previous
//
#include <hip/hip_runtime.h>
#include <math.h>

// InvariantPointAttention — MI355X fp32, round 2: fix parallelism starvation.
// B=1 assumed throughout.
#define N    384
#define DSd  384
#define DP   128
#define DH   16
#define H    12
#define PQK  4
#define PV   8
#define PKV  12
#define HC   (H*DH)          // 192
#define PROJW 1152           // 192 + 384 + 144 + 432
#define NN   (N*N)           // 147456
#define COUTD 2112           // H*(DP + DH + PV*4)

// ---------------------------------------------------------------------------
// Pack the four projection weight matrices (row-major, shared K=384) into one
// 384 x 1152 matrix + concatenated bias, so a single GEMM does all projections.
__global__ __launch_bounds__(256) void pack_w(
    const float* __restrict__ Wq, const float* __restrict__ Wkv,
    const float* __restrict__ Wqp, const float* __restrict__ Wkvp,
    const float* __restrict__ bq, const float* __restrict__ bkv,
    const float* __restrict__ bqp, const float* __restrict__ bkvp,
    float* __restrict__ Wcat, float* __restrict__ bcat)
{
    const int i = blockIdx.x * 256 + threadIdx.x;
    if (i < DSd * PROJW) {
        const int r = i / PROJW, c = i % PROJW;
        float v;
        if (c < 192)      v = Wq[r*192 + c];
        else if (c < 576) v = Wkv[r*384 + (c-192)];
        else if (c < 720) v = Wqp[r*144 + (c-576)];
        else              v = Wkvp[r*432 + (c-720)];
        Wcat[i] = v;
    }
    if (i < PROJW) {
        float v;
        if (i < 192)      v = bq[i];
        else if (i < 576) v = bkv[i-192];
        else if (i < 720) v = bqp[i-576];
        else              v = bkvp[i-720];
        bcat[i] = v;
    }
}

// ---------------------------------------------------------------------------
// Tiled fp32 GEMM, optional split-K. C[r, coff+c] = sum_k A[r,k]*B[k,c] + bias.
// If partial != nullptr: writes raw per-chunk tiles to partial[z][M][Nc].
__global__ __launch_bounds__(256) void gemm_f32(
    const float* __restrict__ A, const float* __restrict__ B,
    const float* __restrict__ bias, float* __restrict__ C,
    int M, int Nc, int K, int ldc, int coff, int kchunk, float* partial)
{
    __shared__ float As[64][33];
    __shared__ float Bs[32][65];
    const int tid = threadIdx.x;
    const int tx = tid & 15, ty = tid >> 4;
    const int row0 = blockIdx.x * 64, col0 = blockIdx.y * 64;
    const int kbeg = blockIdx.z * kchunk;
    const int kend = min(kbeg + kchunk, K);
    float acc[4][4] = {};

    for (int kk = kbeg; kk < kend; kk += 32) {
        #pragma unroll
        for (int i = tid; i < 64*32; i += 256) {
            int r = i >> 5, c = i & 31;
            As[r][c] = A[(row0 + r) * K + kk + c];
        }
        #pragma unroll
        for (int i = tid; i < 32*64; i += 256) {
            int r = i >> 6, c = i & 63;
            int gc = col0 + c;
            Bs[r][c] = (gc < Nc) ? B[(kk + r) * Nc + gc] : 0.f;
        }
        __syncthreads();
        #pragma unroll
        for (int p = 0; p < 32; ++p) {
            float av[4], bv[4];
            #pragma unroll
            for (int i = 0; i < 4; ++i) av[i] = As[ty*4 + i][p];
            #pragma unroll
            for (int j = 0; j < 4; ++j) bv[j] = Bs[p][tx*4 + j];
            #pragma unroll
            for (int i = 0; i < 4; ++i)
                #pragma unroll
                for (int j = 0; j < 4; ++j)
                    acc[i][j] = fmaf(av[i], bv[j], acc[i][j]);
        }
        __syncthreads();
    }
    if (partial) {
        #pragma unroll
        for (int i = 0; i < 4; ++i) {
            int gr = row0 + ty*4 + i;
            #pragma unroll
            for (int j = 0; j < 4; ++j) {
                int gc = col0 + tx*4 + j;
                if (gc < Nc)
                    partial[((size_t)blockIdx.z * M + gr) * Nc + gc] = acc[i][j];
            }
        }
    } else {
        #pragma unroll
        for (int i = 0; i < 4; ++i) {
            int gr = row0 + ty*4 + i;
            #pragma unroll
            for (int j = 0; j < 4; ++j) {
                int gc = col0 + tx*4 + j;
                if (gc < Nc)
                    C[gr * ldc + coff + gc] = acc[i][j] + (bias ? bias[gc] : 0.f);
            }
        }
    }
}

// Sum the 6 split-K partials of the final projection + bias.
__global__ __launch_bounds__(256) void reduce_out(
    const float* __restrict__ partial, const float* __restrict__ bout,
    float* __restrict__ out)
{
    const int i = blockIdx.x * 256 + threadIdx.x;     // 147456 total
    float a = bout[i % 384];
    #pragma unroll
    for (int zc = 0; zc < 6; ++zc) a += partial[zc * NN + i];
    out[i] = a;
}

// ---------------------------------------------------------------------------
// Repack projections + apply frame rotation to points.
__global__ __launch_bounds__(192) void repack_kernel(
    const float* __restrict__ proj, const float* __restrict__ rot,
    const float* __restrict__ trans,
    float* __restrict__ q_t, float* __restrict__ k_t, float* __restrict__ v_t,
    float* __restrict__ qpts_t, float* __restrict__ kpts_t, float* __restrict__ vpts_t)
{
    const int n = blockIdx.x;
    const int tid = threadIdx.x;
    const float* pr = proj + n * PROJW;

    {   // q/k/v transpose to (H, N, DH)
        int h = tid >> 4, d = tid & 15;
        q_t[(h*N + n)*DH + d] = pr[h*DH + d];
        k_t[(h*N + n)*DH + d] = pr[HC + h*2*DH + d];
        v_t[(h*N + n)*DH + d] = pr[HC + h*2*DH + DH + d];
    }
    const float r00 = rot[n*9+0], r01 = rot[n*9+1], r02 = rot[n*9+2];
    const float r10 = rot[n*9+3], r11 = rot[n*9+4], r12 = rot[n*9+5];
    const float r20 = rot[n*9+6], r21 = rot[n*9+7], r22 = rot[n*9+8];
    const float t0 = trans[n*3+0], t1 = trans[n*3+1], t2 = trans[n*3+2];

    if (tid < H*PQK) {  // 48 query points
        int p = tid;
        float l0 = pr[576 + 0*48 + p];
        float l1 = pr[576 + 1*48 + p];
        float l2 = pr[576 + 2*48 + p];
        int h = p / PQK, pt = p % PQK;
        float* dst = qpts_t + (h*N + n)*12 + pt*3;
        dst[0] = r00*l0 + r01*l1 + r02*l2 + t0;
        dst[1] = r10*l0 + r11*l1 + r12*l2 + t1;
        dst[2] = r20*l0 + r21*l1 + r22*l2 + t2;
    }
    if (tid < H*PKV) {  // 144 kv points
        int p = tid;
        float l0 = pr[720 + 0*144 + p];
        float l1 = pr[720 + 1*144 + p];
        float l2 = pr[720 + 2*144 + p];
        int h = p / PKV, pt = p % PKV;
        float x0 = r00*l0 + r01*l1 + r02*l2 + t0;
        float x1 = r10*l0 + r11*l1 + r12*l2 + t1;
        float x2 = r20*l0 + r21*l1 + r22*l2 + t2;
        if (pt < PQK) {
            float* dst = kpts_t + (h*N + n)*12 + pt*3;
            dst[0] = x0; dst[1] = x1; dst[2] = x2;
        } else {
            float* dst = vpts_t + (h*N + n)*24 + (pt - PQK)*3;
            dst[0] = x0; dst[1] = x1; dst[2] = x2;
        }
    }
}

// ---------------------------------------------------------------------------
// bias_t[h][pair] = (z[pair,:] . Wb[:,h] + bb[h]) * sqrt(1/3), stored (H,N,N).
// Wb read as wave-uniform scalar loads (readfirstlane) -> SGPR broadcast.
__global__ __launch_bounds__(256) void bias_kernel(
    const float* __restrict__ z, const float* __restrict__ Wb,
    const float* __restrict__ bb, float* __restrict__ biasattn)
{
    __shared__ float zt[64][DP+1];      // (p+c)%32 banks: 2-way max (free)
    const int tid = threadIdx.x;
    const int base = blockIdx.x * 64;
    for (int i = tid; i < 64*DP; i += 256)
        zt[i >> 7][i & 127] = z[base*DP + i];       // coalesced
    __syncthreads();

    const int p = tid & 63;
    const int g3 = __builtin_amdgcn_readfirstlane((tid >> 6) * 3);  // wave-uniform
    float a0 = 0.f, a1 = 0.f, a2 = 0.f;
    #pragma unroll 4
    for (int c = 0; c < DP; ++c) {
        float zv = zt[p][c];
        a0 = fmaf(zv, Wb[c*H + g3 + 0], a0);        // s_load (uniform)
        a1 = fmaf(zv, Wb[c*H + g3 + 1], a1);
        a2 = fmaf(zv, Wb[c*H + g3 + 2], a2);
    }
    const float sc = 0.5773502691896258f;           // sqrt(1/3)
    const int pair = base + p;
    biasattn[(g3+0)*NN + pair] = (a0 + bb[g3+0]) * sc;
    biasattn[(g3+1)*NN + pair] = (a1 + bb[g3+1]) * sc;
    biasattn[(g3+2)*NN + pair] = (a2 + bb[g3+2]) * sc;
}

// ---------------------------------------------------------------------------
// Per (h, q): logits over k, softmax, write attention in place over bias.
__global__ __launch_bounds__(128) void attn_kernel(
    const float* __restrict__ q_t, const float* __restrict__ k_t,
    const float* __restrict__ qpts_t, const float* __restrict__ kpts_t,
    const float* __restrict__ mask, const float* __restrict__ head_weights,
    float* __restrict__ biasattn)
{
    const int h  = blockIdx.x % H;
    const int qi = blockIdx.x / H;
    const int tid = threadIdx.x;
    __shared__ float qv[DH];
    __shared__ float qp[12];
    __shared__ float logits[N];
    __shared__ float red[128];

    if (tid < DH) qv[tid] = q_t[(h*N + qi)*DH + tid];
    if (tid < 12) qp[tid] = qpts_t[(h*N + qi)*12 + tid];
    __syncthreads();
    const float hw = log1pf(expf(head_weights[h])) * 0.13608276348795434f; // sqrt(1/54)

    float lmax = -1e30f;
    for (int k = tid; k < N; k += 128) {
        const float* kr = k_t + (h*N + k)*DH;
        float dot = 0.f;
        #pragma unroll
        for (int d = 0; d < DH; ++d) dot = fmaf(qv[d], kr[d], dot);
        const float* kp = kpts_t + (h*N + k)*12;
        float d2 = 0.f;
        #pragma unroll
        for (int t = 0; t < 12; ++t) { float df = qp[t] - kp[t]; d2 = fmaf(df, df, d2); }
        float l = dot * 0.14433756729740643f          // sqrt(1/(3*16))
                + biasattn[h*NN + qi*N + k]           // already *sqrt(1/3)
                + mask[qi*N + k]
                - 0.5f * hw * d2;
        logits[k] = l;
        lmax = fmaxf(lmax, l);
    }
    red[tid] = lmax; __syncthreads();
    for (int s = 64; s > 0; s >>= 1) {
        if (tid < s) red[tid] = fmaxf(red[tid], red[tid + s]);
        __syncthreads();
    }
    const float m = red[0];
    __syncthreads();
    float lsum = 0.f;
    for (int k = tid; k < N; k += 128) {
        float e = expf(logits[k] - m);
        logits[k] = e;
        lsum += e;
    }
    red[tid] = lsum; __syncthreads();
    for (int s = 64; s > 0; s >>= 1) {
        if (tid < s) red[tid] += red[tid + s];
        __syncthreads();
    }
    const float inv = 1.f / red[0];
    for (int k = tid; k < N; k += 128)
        biasattn[h*NN + qi*N + k] = logits[k] * inv;
}

// ---------------------------------------------------------------------------
// Per q: o (12x16), o_pts (12x8x3 + norms), o_pair (12x128) -> cat row (2112).
// z row read exactly ONCE per block; k split across the 4 waves.
__global__ __launch_bounds__(256) void out_accum_kernel(
    const float* __restrict__ attn, const float* __restrict__ v_t,
    const float* __restrict__ vpts_t, const float* __restrict__ z,
    const float* __restrict__ rot, const float* __restrict__ trans,
    float* __restrict__ cat)
{
    const int qi = blockIdx.x;
    const int tid = threadIdx.x;
    __shared__ float at[H][N + 1];      // 18.5 KB
    __shared__ float pz[4][H][DP];      // 24 KB: per-wave o_pair partials
    __shared__ float catv[COUTD];       // 8.4 KB
    __shared__ float praw[H*PV*3];      // 1.2 KB

    for (int i = tid; i < H*N; i += 256)
        at[i / N][i % N] = attn[(i / N)*NN + qi*N + (i % N)];
    __syncthreads();

    {   // o_pair: lane owns 2 channels, wave owns a k-quarter (96)
        const int c2 = (tid & 63) * 2;
        const int kq = tid >> 6;
        float acc0[12] = {}, acc1[12] = {};
        const float* zr = z + ((size_t)qi*N + kq*96)*DP + c2;
        #pragma unroll 2
        for (int k = 0; k < 96; ++k) {
            const float2 zv = *(const float2*)(zr + k*DP);   // 8B/lane, coalesced
            #pragma unroll
            for (int h = 0; h < 12; ++h) {
                float a = at[h][kq*96 + k];                  // wave-uniform broadcast
                acc0[h] = fmaf(a, zv.x, acc0[h]);
                acc1[h] = fmaf(a, zv.y, acc1[h]);
            }
        }
        #pragma unroll
        for (int h = 0; h < 12; ++h) {
            pz[kq][h][c2]   = acc0[h];
            pz[kq][h][c2+1] = acc1[h];
        }
    }
    if (tid < H*DH) {   // o
        const int h = tid >> 4, d = tid & 15;
        float acc = 0.f;
        #pragma unroll 4
        for (int k = 0; k < N; ++k)
            acc = fmaf(at[h][k], v_t[(h*N + k)*DH + d], acc);
        catv[h*DH + d] = acc;
    }
    for (int j = tid; j < H*PV*3; j += 256) {   // o_pts accumulate (lab frame)
        const int h = j / 24, r = j % 24;
        float acc = 0.f;
        #pragma unroll 4
        for (int k = 0; k < N; ++k)
            acc = fmaf(at[h][k], vpts_t[(h*N + k)*24 + r], acc);
        praw[j] = acc;
    }
    __syncthreads();
    for (int i = tid; i < H*DP; i += 256) {     // combine o_pair quarters
        int h = i >> 7, c = i & 127;
        catv[576 + i] = pz[0][h][c] + pz[1][h][c] + pz[2][h][c] + pz[3][h][c];
    }
    if (tid < H*PV) {   // inverse rotation (rot^T), translate, norm
        const float* rr = rot + qi*9;
        const float t0 = trans[qi*3+0], t1 = trans[qi*3+1], t2 = trans[qi*3+2];
        float y0 = praw[tid*3+0] - t0;
        float y1 = praw[tid*3+1] - t1;
        float y2 = praw[tid*3+2] - t2;
        float f0 = rr[0]*y0 + rr[3]*y1 + rr[6]*y2;
        float f1 = rr[1]*y0 + rr[4]*y1 + rr[7]*y2;
        float f2 = rr[2]*y0 + rr[5]*y1 + rr[8]*y2;
        catv[HC + 0*96 + tid] = f0;
        catv[HC + 1*96 + tid] = f1;
        catv[HC + 2*96 + tid] = f2;
        catv[HC + 3*96 + tid] = sqrtf(f0*f0 + f1*f1 + f2*f2 + 1e-8f);
    }
    __syncthreads();
    float* dst = cat + (size_t)qi * COUTD;
    for (int i = tid; i < COUTD; i += 256) dst[i] = catv[i];
}

// ---------------------------------------------------------------------------
extern "C" void kernel_launch(void* const* d_in, const int* in_sizes, int n_in,
                              void* d_out, int out_size, void* d_ws, size_t ws_size,
                              hipStream_t stream)
{
    const float* s       = (const float*)d_in[0];
    const float* z       = (const float*)d_in[1];
    const float* rot     = (const float*)d_in[2];
    const float* trans   = (const float*)d_in[3];
    const float* mask    = (const float*)d_in[4];
    const float* Wq      = (const float*)d_in[5];
    const float* bq      = (const float*)d_in[6];
    const float* Wkv     = (const float*)d_in[7];
    const float* bkv     = (const float*)d_in[8];
    const float* Wq_pts  = (const float*)d_in[9];
    const float* bq_pts  = (const float*)d_in[10];
    const float* Wkv_pts = (const float*)d_in[11];
    const float* bkv_pts = (const float*)d_in[12];
    const float* Wb      = (const float*)d_in[13];
    const float* bb      = (const float*)d_in[14];
    const float* hwts    = (const float*)d_in[15];
    const float* Wout    = (const float*)d_in[16];
    const float* bout    = (const float*)d_in[17];
    float* out = (float*)d_out;
    float* ws  = (float*)d_ws;

    // workspace layout (floats); total ~13.9 MB
    float* proj   = ws;                  // N x 1152
    float* q_t    = proj   + 442368;     // H x N x 16
    float* k_t    = q_t    + 73728;
    float* v_t    = k_t    + 73728;
    float* qpts_t = v_t    + 73728;      // H x N x 12
    float* kpts_t = qpts_t + 55296;
    float* vpts_t = kpts_t + 55296;      // H x N x 24
    float* ba     = vpts_t + 110592;     // H x N x N
    float* cat    = ba     + 1769472;    // N x 2112
    float* bcat   = cat    + 811008;     // 1152
    // aliases (stream-ordered, lifetime-disjoint):
    float* Wcat    = ba;                 // 442368, consumed before bias_kernel
    float* partial = ws;                 // 884736 = proj..vpts, used after out_accum

    pack_w<<<1728, 256, 0, stream>>>(Wq, Wkv, Wq_pts, Wkv_pts, bq, bkv, bq_pts, bkv_pts, Wcat, bcat);
    // all projections in one GEMM: (384 x 384) @ (384 x 1152)
    gemm_f32<<<dim3(6,18,1), 256, 0, stream>>>(s, Wcat, bcat, proj, N, PROJW, DSd, PROJW, 0, DSd, nullptr);
    repack_kernel<<<N, 192, 0, stream>>>(proj, rot, trans, q_t, k_t, v_t, qpts_t, kpts_t, vpts_t);
    bias_kernel<<<NN/64, 256, 0, stream>>>(z, Wb, bb, ba);
    attn_kernel<<<N*H, 128, 0, stream>>>(q_t, k_t, qpts_t, kpts_t, mask, hwts, ba);
    out_accum_kernel<<<N, 256, 0, stream>>>(ba, v_t, vpts_t, z, rot, trans, cat);
    // final projection with split-K=6: (384 x 2112) @ (2112 x 384), 216 blocks
    gemm_f32<<<dim3(6,6,6), 256, 0, stream>>>(cat, Wout, nullptr, nullptr, N, 384, COUTD, 384, 0, 352, partial);
    reduce_out<<<NN/256, 256, 0, stream>>>(partial, bout, out);
}

// Round 3
// 278.391 us; speedup vs baseline: 2.7722x; 1.4494x over previous
//
#include <hip/hip_runtime.h>
#include <math.h>

// InvariantPointAttention — MI355X fp32, round 3: kill grid starvation everywhere.
// B=1 assumed.
#define N     384
#define DSd   384
#define DP    128
#define DH    16
#define H     12
#define PQK   4
#define PV    8
#define HC    (H*DH)          // 192
#define PROJW 1152
#define NN    (N*N)           // 147456
#define COUTD 2112
#define KSPL  4
#define KCH   96              // N / KSPL

// ---------------------------------------------------------------------------
__global__ __launch_bounds__(256) void pack_w(
    const float* __restrict__ Wq, const float* __restrict__ Wkv,
    const float* __restrict__ Wqp, const float* __restrict__ Wkvp,
    const float* __restrict__ bq, const float* __restrict__ bkv,
    const float* __restrict__ bqp, const float* __restrict__ bkvp,
    float* __restrict__ Wcat, float* __restrict__ bcat)
{
    const int i = blockIdx.x * 256 + threadIdx.x;
    if (i < DSd * PROJW) {
        const int r = i / PROJW, c = i % PROJW;
        float v;
        if (c < 192)      v = Wq[r*192 + c];
        else if (c < 576) v = Wkv[r*384 + (c-192)];
        else if (c < 720) v = Wqp[r*144 + (c-576)];
        else              v = Wkvp[r*432 + (c-720)];
        Wcat[i] = v;
    }
    if (i < PROJW) {
        float v;
        if (i < 192)      v = bq[i];
        else if (i < 576) v = bkv[i-192];
        else if (i < 720) v = bqp[i-576];
        else              v = bkvp[i-720];
        bcat[i] = v;
    }
}

// ---------------------------------------------------------------------------
// 32x64-tile fp32 GEMM with split-K; always writes raw partials.
// partial[z][M][Nc]. M%32==0, Nc%64==0, kchunk%32==0.
__global__ __launch_bounds__(256) void gemm32x64(
    const float* __restrict__ A, const float* __restrict__ B,
    float* __restrict__ partial, int M, int Nc, int K, int kchunk)
{
    __shared__ float Ast[32][34];   // [k][row]; float2 reads stay 8B-aligned
    __shared__ float Bs[32][68];    // [k][col]; float4 reads stay 16B-aligned
    const int tid = threadIdx.x;
    const int tc = tid & 15, tr = tid >> 4;        // cols tc*4.., rows tr*2..
    const int row0 = blockIdx.x * 32, col0 = blockIdx.y * 64;
    const int kbeg = blockIdx.z * kchunk;
    const int kend = kbeg + kchunk;
    float acc[2][4] = {};

    for (int kk = kbeg; kk < kend; kk += 32) {
        #pragma unroll
        for (int i = tid; i < 32*32; i += 256) {    // A tile, store transposed
            int r = i >> 5, c = i & 31;
            Ast[c][r] = A[(row0 + r) * K + kk + c];
        }
        #pragma unroll
        for (int i = tid; i < 32*64; i += 256) {    // B tile
            int r = i >> 6, c = i & 63;
            Bs[r][c] = B[(kk + r) * Nc + col0 + c];
        }
        __syncthreads();
        #pragma unroll
        for (int p = 0; p < 32; ++p) {
            const float2 av = *(const float2*)&Ast[p][tr*2];
            const float4 bv = *(const float4*)&Bs[p][tc*4];
            acc[0][0] = fmaf(av.x, bv.x, acc[0][0]);
            acc[0][1] = fmaf(av.x, bv.y, acc[0][1]);
            acc[0][2] = fmaf(av.x, bv.z, acc[0][2]);
            acc[0][3] = fmaf(av.x, bv.w, acc[0][3]);
            acc[1][0] = fmaf(av.y, bv.x, acc[1][0]);
            acc[1][1] = fmaf(av.y, bv.y, acc[1][1]);
            acc[1][2] = fmaf(av.y, bv.z, acc[1][2]);
            acc[1][3] = fmaf(av.y, bv.w, acc[1][3]);
        }
        __syncthreads();
    }
    float* p0 = partial + ((size_t)blockIdx.z * M + row0 + tr*2) * Nc + col0 + tc*4;
    *(float4*)p0        = make_float4(acc[0][0], acc[0][1], acc[0][2], acc[0][3]);
    *(float4*)(p0 + Nc) = make_float4(acc[1][0], acc[1][1], acc[1][2], acc[1][3]);
}

// out[i] = bias[i % nc] + sum_{t<parts} partial[t*stride + i]
__global__ __launch_bounds__(256) void reduce_kernel(
    const float* __restrict__ partial, const float* __restrict__ bias,
    float* __restrict__ out, int nc, int parts, int stride)
{
    const int i = blockIdx.x * 256 + threadIdx.x;
    float a = bias[i % nc];
    for (int t = 0; t < parts; ++t) a += partial[(size_t)t * stride + i];
    out[i] = a;
}

// ---------------------------------------------------------------------------
// Repack projections + frame rotation. vcat packs v (16) ‖ v_pts (24) per (h,n).
__global__ __launch_bounds__(192) void repack_kernel(
    const float* __restrict__ proj, const float* __restrict__ rot,
    const float* __restrict__ trans,
    float* __restrict__ q_t, float* __restrict__ k_t, float* __restrict__ vcat,
    float* __restrict__ qpts_t, float* __restrict__ kpts_t)
{
    const int n = blockIdx.x;
    const int tid = threadIdx.x;
    const float* pr = proj + n * PROJW;

    {
        int h = tid >> 4, d = tid & 15;
        q_t[(h*N + n)*DH + d]   = pr[h*DH + d];
        k_t[(h*N + n)*DH + d]   = pr[HC + h*2*DH + d];
        vcat[(h*N + n)*40 + d]  = pr[HC + h*2*DH + DH + d];
    }
    const float r00 = rot[n*9+0], r01 = rot[n*9+1], r02 = rot[n*9+2];
    const float r10 = rot[n*9+3], r11 = rot[n*9+4], r12 = rot[n*9+5];
    const float r20 = rot[n*9+6], r21 = rot[n*9+7], r22 = rot[n*9+8];
    const float t0 = trans[n*3+0], t1 = trans[n*3+1], t2 = trans[n*3+2];

    if (tid < H*PQK) {
        int p = tid;
        float l0 = pr[576 + 0*48 + p];
        float l1 = pr[576 + 1*48 + p];
        float l2 = pr[576 + 2*48 + p];
        int h = p / PQK, pt = p % PQK;
        float* dst = qpts_t + (h*N + n)*12 + pt*3;
        dst[0] = r00*l0 + r01*l1 + r02*l2 + t0;
        dst[1] = r10*l0 + r11*l1 + r12*l2 + t1;
        dst[2] = r20*l0 + r21*l1 + r22*l2 + t2;
    }
    if (tid < H*(PQK+PV)) {
        int p = tid;
        float l0 = pr[720 + 0*144 + p];
        float l1 = pr[720 + 1*144 + p];
        float l2 = pr[720 + 2*144 + p];
        int h = p / 12, pt = p % 12;
        float x0 = r00*l0 + r01*l1 + r02*l2 + t0;
        float x1 = r10*l0 + r11*l1 + r12*l2 + t1;
        float x2 = r20*l0 + r21*l1 + r22*l2 + t2;
        if (pt < PQK) {
            float* dst = kpts_t + (h*N + n)*12 + pt*3;
            dst[0] = x0; dst[1] = x1; dst[2] = x2;
        } else {
            float* dst = vcat + (h*N + n)*40 + 16 + (pt - PQK)*3;
            dst[0] = x0; dst[1] = x1; dst[2] = x2;
        }
    }
}

// ---------------------------------------------------------------------------
// bias_t[h][pair] = (z[pair,:] . Wb[:,h] + bb[h]) * sqrt(1/3), stored (H,N,N).
__global__ __launch_bounds__(256) void bias_kernel(
    const float* __restrict__ z, const float* __restrict__ Wb,
    const float* __restrict__ bb, float* __restrict__ biasattn)
{
    __shared__ float zt[64][DP+1];
    const int tid = threadIdx.x;
    const int base = blockIdx.x * 64;
    for (int i = tid; i < 64*DP; i += 256)
        zt[i >> 7][i & 127] = z[(size_t)base*DP + i];
    __syncthreads();

    const int p = tid & 63;
    const int g3 = __builtin_amdgcn_readfirstlane((tid >> 6) * 3);
    float a0 = 0.f, a1 = 0.f, a2 = 0.f;
    #pragma unroll 4
    for (int c = 0; c < DP; ++c) {
        float zv = zt[p][c];
        a0 = fmaf(zv, Wb[c*H + g3 + 0], a0);
        a1 = fmaf(zv, Wb[c*H + g3 + 1], a1);
        a2 = fmaf(zv, Wb[c*H + g3 + 2], a2);
    }
    const float sc = 0.5773502691896258f;
    const int pair = base + p;
    biasattn[(g3+0)*NN + pair] = (a0 + bb[g3+0]) * sc;
    biasattn[(g3+1)*NN + pair] = (a1 + bb[g3+1]) * sc;
    biasattn[(g3+2)*NN + pair] = (a2 + bb[g3+2]) * sc;
}

// ---------------------------------------------------------------------------
__global__ __launch_bounds__(128) void attn_kernel(
    const float* __restrict__ q_t, const float* __restrict__ k_t,
    const float* __restrict__ qpts_t, const float* __restrict__ kpts_t,
    const float* __restrict__ mask, const float* __restrict__ head_weights,
    float* __restrict__ biasattn)
{
    const int h  = blockIdx.x % H;
    const int qi = blockIdx.x / H;
    const int tid = threadIdx.x;
    __shared__ float logits[N];
    __shared__ float red[4];

    const float4* qv = (const float4*)(q_t + (h*N + qi)*DH);
    const float4 q0 = qv[0], q1 = qv[1], q2 = qv[2], q3 = qv[3];
    const float4* qpv = (const float4*)(qpts_t + (h*N + qi)*12);
    const float4 p0 = qpv[0], p1 = qpv[1], p2 = qpv[2];
    const float hw = log1pf(expf(head_weights[h])) * 0.13608276348795434f; // sqrt(1/54)

    float lmax = -1e30f;
    for (int k = tid; k < N; k += 128) {
        const float4* kr = (const float4*)(k_t + (h*N + k)*DH);
        const float4 a0 = kr[0], a1 = kr[1], a2 = kr[2], a3 = kr[3];
        float dot = q0.x*a0.x;
        dot = fmaf(q0.y, a0.y, dot); dot = fmaf(q0.z, a0.z, dot); dot = fmaf(q0.w, a0.w, dot);
        dot = fmaf(q1.x, a1.x, dot); dot = fmaf(q1.y, a1.y, dot); dot = fmaf(q1.z, a1.z, dot); dot = fmaf(q1.w, a1.w, dot);
        dot = fmaf(q2.x, a2.x, dot); dot = fmaf(q2.y, a2.y, dot); dot = fmaf(q2.z, a2.z, dot); dot = fmaf(q2.w, a2.w, dot);
        dot = fmaf(q3.x, a3.x, dot); dot = fmaf(q3.y, a3.y, dot); dot = fmaf(q3.z, a3.z, dot); dot = fmaf(q3.w, a3.w, dot);
        const float4* kp = (const float4*)(kpts_t + (h*N + k)*12);
        const float4 b0 = kp[0], b1 = kp[1], b2 = kp[2];
        float df, d2;
        df = p0.x-b0.x; d2 = df*df;
        df = p0.y-b0.y; d2 = fmaf(df, df, d2);
        df = p0.z-b0.z; d2 = fmaf(df, df, d2);
        df = p0.w-b0.w; d2 = fmaf(df, df, d2);
        df = p1.x-b1.x; d2 = fmaf(df, df, d2);
        df = p1.y-b1.y; d2 = fmaf(df, df, d2);
        df = p1.z-b1.z; d2 = fmaf(df, df, d2);
        df = p1.w-b1.w; d2 = fmaf(df, df, d2);
        df = p2.x-b2.x; d2 = fmaf(df, df, d2);
        df = p2.y-b2.y; d2 = fmaf(df, df, d2);
        df = p2.z-b2.z; d2 = fmaf(df, df, d2);
        df = p2.w-b2.w; d2 = fmaf(df, df, d2);
        float l = fmaf(dot, 0.14433756729740643f,
                       biasattn[h*NN + qi*N + k] + mask[qi*N + k])
                - 0.5f * hw * d2;
        logits[k] = l;
        lmax = fmaxf(lmax, l);
    }
    #pragma unroll
    for (int o = 32; o > 0; o >>= 1) lmax = fmaxf(lmax, __shfl_xor(lmax, o));
    if ((tid & 63) == 0) red[tid >> 6] = lmax;
    __syncthreads();
    const float m = fmaxf(red[0], red[1]);
    float lsum = 0.f;
    for (int k = tid; k < N; k += 128) {
        float e = __expf(logits[k] - m);
        logits[k] = e;
        lsum += e;
    }
    #pragma unroll
    for (int o = 32; o > 0; o >>= 1) lsum += __shfl_xor(lsum, o);
    if ((tid & 63) == 0) red[2 + (tid >> 6)] = lsum;
    __syncthreads();
    const float inv = 1.f / (red[2] + red[3]);
    for (int k = tid; k < N; k += 128)
        biasattn[h*NN + qi*N + k] = logits[k] * inv;
}

// ---------------------------------------------------------------------------
// Split-k output accumulation. Block (qi, kq) covers k in [kq*96, kq*96+96).
// attn values are wave-uniform -> scalar (s_load) broadcast; z in VGPRs.
__global__ __launch_bounds__(256) void opair_partial(
    const float* __restrict__ attn, const float* __restrict__ vcat,
    const float* __restrict__ z, float* __restrict__ P1, float* __restrict__ P2)
{
    const int qi = blockIdx.x, kq = blockIdx.y;
    const int k0 = kq * KCH;
    const int tid = threadIdx.x;
    __shared__ float pzs[2][H][DP];   // 12 KB

    {   // o_pair: lane owns channel c; wave-pair owns 48 of the 96 k's
        const int c = tid & 127;
        const int halfu = __builtin_amdgcn_readfirstlane(tid >> 7);
        const float* zp = z + ((size_t)qi*N + k0 + halfu*48)*DP + c;
        float zreg[48];
        #pragma unroll
        for (int k = 0; k < 48; ++k) zreg[k] = zp[(size_t)k*DP];
        const float* arow = attn + qi*N + k0 + halfu*48;   // + h*NN, uniform
        #pragma unroll
        for (int h = 0; h < H; ++h) {
            float a = 0.f;
            #pragma unroll
            for (int k = 0; k < 48; ++k)
                a = fmaf(arow[h*NN + k], zreg[k], a);
            pzs[halfu][h][c] = a;
        }
    }
    {   // o (16) and o_pts (24) per head; wave -> 3 heads; lanes 0..39 active
        const int wv = tid >> 6, lane = tid & 63;
        if (lane < 40) {
            #pragma unroll
            for (int ih = 0; ih < 3; ++ih) {
                const int h = wv*3 + ih;
                const float* arow2 = attn + h*NN + qi*N + k0;   // uniform
                const float* vp = vcat + ((size_t)h*N + k0)*40 + lane;
                float a = 0.f;
                #pragma unroll 4
                for (int k = 0; k < KCH; ++k)
                    a = fmaf(arow2[k], vp[k*40], a);
                const int j = (lane < 16) ? h*16 + lane : 192 + h*24 + (lane-16);
                P1[((size_t)qi*KSPL + kq)*480 + j] = a;
            }
        }
    }
    __syncthreads();
    for (int i = tid; i < H*DP; i += 256)
        P2[((size_t)qi*KSPL + kq)*(H*DP) + i] = pzs[0][i>>7][i&127] + pzs[1][i>>7][i&127];
}

// ---------------------------------------------------------------------------
// Per-q: sum split-k partials, inverse-frame o_pts + norms, assemble cat row.
__global__ __launch_bounds__(256) void combine_kernel(
    const float* __restrict__ P1, const float* __restrict__ P2,
    const float* __restrict__ rot, const float* __restrict__ trans,
    float* __restrict__ cat)
{
    const int qi = blockIdx.x;
    const int tid = threadIdx.x;
    __shared__ float catv[COUTD];
    __shared__ float praw[H*PV*3];

    for (int j = tid; j < 480; j += 256) {
        const float* p = P1 + (size_t)qi*KSPL*480 + j;
        float s = p[0] + p[480] + p[960] + p[1440];
        if (j < 192) catv[j] = s; else praw[j-192] = s;
    }
    for (int i = tid; i < H*DP; i += 256) {
        const float* p = P2 + (size_t)qi*KSPL*(H*DP) + i;
        catv[576 + i] = p[0] + p[1536] + p[3072] + p[4608];
    }
    __syncthreads();
    if (tid < H*PV) {
        const float* rr = rot + qi*9;
        const float t0 = trans[qi*3+0], t1 = trans[qi*3+1], t2 = trans[qi*3+2];
        float y0 = praw[tid*3+0] - t0;
        float y1 = praw[tid*3+1] - t1;
        float y2 = praw[tid*3+2] - t2;
        float f0 = rr[0]*y0 + rr[3]*y1 + rr[6]*y2;
        float f1 = rr[1]*y0 + rr[4]*y1 + rr[7]*y2;
        float f2 = rr[2]*y0 + rr[5]*y1 + rr[8]*y2;
        catv[HC + 0*96 + tid] = f0;
        catv[HC + 1*96 + tid] = f1;
        catv[HC + 2*96 + tid] = f2;
        catv[HC + 3*96 + tid] = sqrtf(f0*f0 + f1*f1 + f2*f2 + 1e-8f);
    }
    __syncthreads();
    float4* dst = (float4*)(cat + (size_t)qi * COUTD);
    const float4* src = (const float4*)catv;
    for (int i = tid; i < COUTD/4; i += 256) dst[i] = src[i];
}

// ---------------------------------------------------------------------------
extern "C" void kernel_launch(void* const* d_in, const int* in_sizes, int n_in,
                              void* d_out, int out_size, void* d_ws, size_t ws_size,
                              hipStream_t stream)
{
    const float* s       = (const float*)d_in[0];
    const float* z       = (const float*)d_in[1];
    const float* rot     = (const float*)d_in[2];
    const float* trans   = (const float*)d_in[3];
    const float* mask    = (const float*)d_in[4];
    const float* Wq      = (const float*)d_in[5];
    const float* bq      = (const float*)d_in[6];
    const float* Wkv     = (const float*)d_in[7];
    const float* bkv     = (const float*)d_in[8];
    const float* Wq_pts  = (const float*)d_in[9];
    const float* bq_pts  = (const float*)d_in[10];
    const float* Wkv_pts = (const float*)d_in[11];
    const float* bkv_pts = (const float*)d_in[12];
    const float* Wb      = (const float*)d_in[13];
    const float* bb      = (const float*)d_in[14];
    const float* hwts    = (const float*)d_in[15];
    const float* Wout    = (const float*)d_in[16];
    const float* bout    = (const float*)d_in[17];
    float* out = (float*)d_out;
    float* ws  = (float*)d_ws;

    // ---- workspace layout (floats), total ~23.3 MiB ----
    float* ba     = ws;                    // 1,769,472  (bias -> attn in place)
    float* cat    = ba     + 1769472;      //   811,008
    float* q_t    = cat    + 811008;       //    73,728
    float* k_t    = q_t    + 73728;        //    73,728
    float* qpts_t = k_t    + 73728;        //    55,296
    float* kpts_t = qpts_t + 55296;        //    55,296
    float* vcat   = kpts_t + 55296;        //   184,320  (H,N,40)
    float* X      = vcat   + 184320;       // shared region, 3,096,576
    // early phase:
    float* proj     = X;                   //   442,368
    float* partialP = X + 442368;          //   884,736
    float* Wcat     = X + 1327104;         //   442,368
    float* bcat     = X + 1769472;         //     1,152
    // late phase (early dead after repack):
    float* P1       = X;                   //   737,280
    float* P2       = X + 737280;          // 2,359,296
    float* partialF = X;                   // 1,622,016 (after combine; P1/P2 dead)

    pack_w<<<1728, 256, 0, stream>>>(Wq, Wkv, Wq_pts, Wkv_pts, bq, bkv, bq_pts, bkv_pts, Wcat, bcat);
    // projections: (384 x 384) @ (384 x 1152), split-K 2 -> 432 blocks
    gemm32x64<<<dim3(12,18,2), 256, 0, stream>>>(s, Wcat, partialP, N, PROJW, DSd, 192);
    reduce_kernel<<<1728, 256, 0, stream>>>(partialP, bcat, proj, PROJW, 2, 442368);
    repack_kernel<<<N, 192, 0, stream>>>(proj, rot, trans, q_t, k_t, vcat, qpts_t, kpts_t);
    bias_kernel<<<NN/64, 256, 0, stream>>>(z, Wb, bb, ba);
    attn_kernel<<<N*H, 128, 0, stream>>>(q_t, k_t, qpts_t, kpts_t, mask, hwts, ba);
    opair_partial<<<dim3(N, KSPL), 256, 0, stream>>>(ba, vcat, z, P1, P2);
    combine_kernel<<<N, 256, 0, stream>>>(P1, P2, rot, trans, cat);
    // final projection: (384 x 2112) @ (2112 x 384), split-K 11 -> 792 blocks
    gemm32x64<<<dim3(12,6,11), 256, 0, stream>>>(cat, Wout, partialF, N, 384, COUTD, 192);
    reduce_kernel<<<576, 256, 0, stream>>>(partialF, bout, out, 384, 11, NN);
}